// Round 4
// baseline (1705.483 us; speedup 1.0000x reference)
//
#include <hip/hip_runtime.h>

typedef __attribute__((ext_vector_type(4))) float  f32x4;
typedef __attribute__((ext_vector_type(2))) float  f32x2;
typedef __attribute__((ext_vector_type(8))) __bf16 bf16x8;
typedef __attribute__((ext_vector_type(4))) short  s16x4;
typedef __attribute__((ext_vector_type(8))) short  s16x8;
typedef unsigned char uchar;

__device__ __forceinline__ unsigned short f2bf(float f) {
  unsigned u = __builtin_bit_cast(unsigned, f);
  u += 0x7FFFu + ((u >> 16) & 1u);
  return (unsigned short)(u >> 16);
}
__device__ __forceinline__ float b2f(short s) {
  return __builtin_bit_cast(float, (unsigned)((unsigned short)s) << 16);
}
__device__ __forceinline__ uchar f2fp8(float v) {
  return (uchar)(__builtin_amdgcn_cvt_pk_fp8_f32(v, v, 0, false) & 0xFF);
}
__device__ __forceinline__ float gelu_fast(float v) {
  float u = v * (0.7978845608f + 0.0356774081f * v * v);
  float t = __expf(-2.f * fabsf(u));
  float th = (1.f - t) / (1.f + t);
  th = (u >= 0.f) ? th : -th;
  return 0.5f * v * (1.f + th);
}

__device__ __forceinline__ void gload16(const void* g, void* l) {
  __builtin_amdgcn_global_load_lds(
      (const __attribute__((address_space(1))) void*)g,
      (__attribute__((address_space(3))) void*)l, 16, 0, 0);
}

// Transpose + cast weights: W [L][In][Out] f32 -> WT [L][Out][In] bf16
__global__ __launch_bounds__(256) void wcast(const float* __restrict__ W,
                                             short* __restrict__ WT,
                                             int In, int Out) {
  int i = blockIdx.x * 256 + threadIdx.x;
  int lay = blockIdx.y;
  if (i >= In * Out) return;
  const float* w = W + (size_t)lay * In * Out;
  short* wt = WT + (size_t)lay * In * Out;
  int ii = i % In, oo = i / In;
  wt[(size_t)oo * In + ii] = (short)f2bf(w[(size_t)ii * Out + oo]);
}

// LayerNorm over C=256, one wave per row, write bf16 (used once, on in_x)
__global__ __launch_bounds__(256) void ln_k(const float* __restrict__ x,
                                            const float* __restrict__ g,
                                            const float* __restrict__ b,
                                            short* __restrict__ out) {
  int row = blockIdx.x * 4 + (threadIdx.x >> 6);
  int l = threadIdx.x & 63;
  const float4 v = *(const float4*)(x + (size_t)row * 256 + l * 4);
  float s  = v.x + v.y + v.z + v.w;
  float ss = v.x * v.x + v.y * v.y + v.z * v.z + v.w * v.w;
#pragma unroll
  for (int o = 32; o >= 1; o >>= 1) {
    s  += __shfl_xor(s, o);
    ss += __shfl_xor(ss, o);
  }
  float mean = s * (1.0f / 256.0f);
  float var  = ss * (1.0f / 256.0f) - mean * mean;
  float rstd = rsqrtf(var + 1e-5f);
  const float4 gg = *(const float4*)(g + l * 4);
  const float4 bb = *(const float4*)(b + l * 4);
  s16x4 o4;
  o4[0] = (short)f2bf((v.x - mean) * rstd * gg.x + bb.x);
  o4[1] = (short)f2bf((v.y - mean) * rstd * gg.y + bb.y);
  o4[2] = (short)f2bf((v.z - mean) * rstd * gg.z + bb.z);
  o4[3] = (short)f2bf((v.w - mean) * rstd * gg.w + bb.w);
  *(s16x4*)(out + (size_t)row * 256 + l * 4) = o4;
}

// KNN attention: one wave per point. q bf16 [N][256], k8/v8 fp8 [N][256]
__global__ __launch_bounds__(256) void attn_k(const short* __restrict__ q_,
                                              const uchar* __restrict__ k8,
                                              const uchar* __restrict__ v8,
                                              const int* __restrict__ knn,
                                              short* __restrict__ out) {
  int n = blockIdx.x * 4 + (threadIdx.x >> 6);
  int l = threadIdx.x & 63;
  int j = l & 15, g = l >> 4;
  int idxj = knn[(size_t)n * 16 + j];
  const short* qp = q_ + (size_t)n * 256 + g * 64;
  const uchar* kp = k8 + (size_t)idxj * 256 + g * 64;
  float partial = 0.f;
#pragma unroll
  for (int t = 0; t < 4; ++t) {  // 16 channels per t
    int4 kv = *(const int4*)(kp + t * 16);
    s16x8 q0 = *(const s16x8*)(qp + t * 16);
    s16x8 q1 = *(const s16x8*)(qp + t * 16 + 8);
    f32x2 a;
    a = __builtin_amdgcn_cvt_pk_f32_fp8(kv.x, false);
    partial += a[0] * b2f(q0[0]) + a[1] * b2f(q0[1]);
    a = __builtin_amdgcn_cvt_pk_f32_fp8(kv.x, true);
    partial += a[0] * b2f(q0[2]) + a[1] * b2f(q0[3]);
    a = __builtin_amdgcn_cvt_pk_f32_fp8(kv.y, false);
    partial += a[0] * b2f(q0[4]) + a[1] * b2f(q0[5]);
    a = __builtin_amdgcn_cvt_pk_f32_fp8(kv.y, true);
    partial += a[0] * b2f(q0[6]) + a[1] * b2f(q0[7]);
    a = __builtin_amdgcn_cvt_pk_f32_fp8(kv.z, false);
    partial += a[0] * b2f(q1[0]) + a[1] * b2f(q1[1]);
    a = __builtin_amdgcn_cvt_pk_f32_fp8(kv.z, true);
    partial += a[0] * b2f(q1[2]) + a[1] * b2f(q1[3]);
    a = __builtin_amdgcn_cvt_pk_f32_fp8(kv.w, false);
    partial += a[0] * b2f(q1[4]) + a[1] * b2f(q1[5]);
    a = __builtin_amdgcn_cvt_pk_f32_fp8(kv.w, true);
    partial += a[0] * b2f(q1[6]) + a[1] * b2f(q1[7]);
  }
  partial += __shfl_xor(partial, 16);
  partial += __shfl_xor(partial, 32);
  float score = partial * 0.0625f;  // C^-0.5, C=256
  float mx = score;
#pragma unroll
  for (int o = 1; o < 16; o <<= 1) mx = fmaxf(mx, __shfl_xor(mx, o));
  float e = __expf(score - mx);
  float sum = e;
#pragma unroll
  for (int o = 1; o < 16; o <<= 1) sum += __shfl_xor(sum, o);
  float attn = e / sum;
  float4 o4 = {0.f, 0.f, 0.f, 0.f};
#pragma unroll
  for (int jj = 0; jj < 16; ++jj) {
    float aj = __shfl(attn, jj);
    int   ij = __shfl(idxj, jj);
    int vv = *(const int*)(v8 + (size_t)ij * 256 + l * 4);
    f32x2 lo = __builtin_amdgcn_cvt_pk_f32_fp8(vv, false);
    f32x2 hi = __builtin_amdgcn_cvt_pk_f32_fp8(vv, true);
    o4.x += aj * lo[0];
    o4.y += aj * lo[1];
    o4.z += aj * hi[0];
    o4.w += aj * hi[1];
  }
  s16x4 ob;
  ob[0] = (short)f2bf(o4.x);
  ob[1] = (short)f2bf(o4.y);
  ob[2] = (short)f2bf(o4.z);
  ob[3] = (short)f2bf(o4.w);
  *(s16x4*)(out + (size_t)n * 256 + l * 4) = ob;
}

// GEMM: A [M][KD] bf16 x BT [Nout][KD] bf16 -> out [M][Nout]
// EPI 2: +bias, fast-gelu -> bf16. EPI 3: qkv split -> q bf16 / k8 / v8 fp8.
// 128x128 tile, BK=64, 4 waves (2x2), T2 XOR swizzle, T1 XCD-chunked swizzle.
template <int EPI, int KD>
__global__ __launch_bounds__(256) void gemm_k(
    const short* __restrict__ A, const short* __restrict__ BT,
    const float* __restrict__ bias, short* __restrict__ outb,
    uchar* __restrict__ k8, uchar* __restrict__ v8, int Nout, int gx) {
  __shared__ __align__(16) short lA[128 * 64];
  __shared__ __align__(16) short lB[128 * 64];
  const int tid = threadIdx.x;
  const int l = tid & 63, w = tid >> 6;
  const int nwg = gridDim.x;
  const int bid = blockIdx.x;
  const int swz = (bid & 7) * (nwg >> 3) + (bid >> 3);
  const int m0 = (swz / gx) << 7, n0 = (swz % gx) << 7;
  const int wm = w >> 1, wn = w & 1;

  f32x4 acc[4][4];
#pragma unroll
  for (int i = 0; i < 4; ++i)
#pragma unroll
    for (int jj = 0; jj < 4; ++jj) acc[i][jj] = f32x4{0.f, 0.f, 0.f, 0.f};

  const int srow = (w << 3) + (l >> 3);
  const int scol = (((l & 7) << 3)) ^ ((srow & 7) << 3);
  const short* gA = A + (size_t)(m0 + srow) * KD + scol;
  const short* gB = BT + (size_t)(n0 + srow) * KD + scol;

  for (int kt = 0; kt < KD; kt += 64) {
#pragma unroll
    for (int it = 0; it < 4; ++it) {
      gload16(gA + (size_t)(it * 32) * KD + kt, &lA[(it * 32 + w * 8) * 64]);
      gload16(gB + (size_t)(it * 32) * KD + kt, &lB[(it * 32 + w * 8) * 64]);
    }
    __syncthreads();
#pragma unroll
    for (int kc = 0; kc < 2; ++kc) {
      bf16x8 aF[4], bF[4];
#pragma unroll
      for (int f = 0; f < 4; ++f) {
        int r = wm * 64 + f * 16 + (l & 15);
        int ce = (kc * 32 + ((l >> 4) << 3)) ^ ((r & 7) << 3);
        aF[f] = *(const bf16x8*)(lA + r * 64 + ce);
      }
#pragma unroll
      for (int f = 0; f < 4; ++f) {
        int r = wn * 64 + f * 16 + (l & 15);
        int ce = (kc * 32 + ((l >> 4) << 3)) ^ ((r & 7) << 3);
        bF[f] = *(const bf16x8*)(lB + r * 64 + ce);
      }
#pragma unroll
      for (int mf = 0; mf < 4; ++mf)
#pragma unroll
        for (int nf = 0; nf < 4; ++nf)
          acc[mf][nf] = __builtin_amdgcn_mfma_f32_16x16x32_bf16(
              aF[mf], bF[nf], acc[mf][nf], 0, 0, 0);
    }
    __syncthreads();
  }

  const int lr = (l >> 4) << 2, lc = l & 15;
#pragma unroll
  for (int mf = 0; mf < 4; ++mf) {
#pragma unroll
    for (int nf = 0; nf < 4; ++nf) {
#pragma unroll
      for (int jj = 0; jj < 4; ++jj) {
        int row = m0 + wm * 64 + mf * 16 + lr + jj;
        int col = n0 + wn * 64 + nf * 16 + lc;
        float v = acc[mf][nf][jj];
        if (EPI == 2) {
          v = gelu_fast(v + bias[col]);
          outb[(size_t)row * Nout + col] = (short)f2bf(v);
        } else {  // EPI 3: qkv split
          if (col < 256)
            outb[(size_t)row * 256 + col] = (short)f2bf(v);
          else if (col < 512)
            k8[(size_t)row * 256 + (col - 256)] = f2fp8(v);
          else
            v8[(size_t)row * 256 + (col - 512)] = f2fp8(v);
        }
      }
    }
  }
}

// GEMM + bias + residual + fused LayerNorm.
// A [M][KD] bf16 x BT [256][KD] bf16; out x f32 [M][256]; act = LN(x) bf16.
// Tile 128 rows x 256 cols (full row), BK=64, 4 waves (2 wm x 2 wn, 64x128 each).
template <int KD>
__global__ __launch_bounds__(256) void gemm_ln(
    const short* __restrict__ A, const short* __restrict__ BT,
    const float* __restrict__ bias, const float* __restrict__ resid,
    float* __restrict__ xout, const float* __restrict__ lng,
    const float* __restrict__ lnb, short* __restrict__ act) {
  __shared__ __align__(16) short lA[128 * 64];
  __shared__ __align__(16) short lB[256 * 64];
  __shared__ float psum[2][128], psq[2][128];
  const int tid = threadIdx.x;
  const int l = tid & 63, w = tid >> 6;
  const int nwg = gridDim.x;  // 512
  const int bid = blockIdx.x;
  const int swz = (bid & 7) * (nwg >> 3) + (bid >> 3);
  const int m0 = swz << 7;
  const int wm = w >> 1, wn = w & 1;

  f32x4 acc[4][8];
#pragma unroll
  for (int i = 0; i < 4; ++i)
#pragma unroll
    for (int jj = 0; jj < 8; ++jj) acc[i][jj] = f32x4{0.f, 0.f, 0.f, 0.f};

  const int srow = (w << 3) + (l >> 3);
  const int scol = (((l & 7) << 3)) ^ ((srow & 7) << 3);
  const short* gA = A + (size_t)(m0 + srow) * KD + scol;
  const short* gB = BT + (size_t)srow * KD + scol;

  for (int kt = 0; kt < KD; kt += 64) {
#pragma unroll
    for (int it = 0; it < 4; ++it)
      gload16(gA + (size_t)(it * 32) * KD + kt, &lA[(it * 32 + w * 8) * 64]);
#pragma unroll
    for (int it = 0; it < 8; ++it)
      gload16(gB + (size_t)(it * 32) * KD + kt, &lB[(it * 32 + w * 8) * 64]);
    __syncthreads();
#pragma unroll
    for (int kc = 0; kc < 2; ++kc) {
      bf16x8 aF[4], bF[8];
#pragma unroll
      for (int f = 0; f < 4; ++f) {
        int r = wm * 64 + f * 16 + (l & 15);
        int ce = (kc * 32 + ((l >> 4) << 3)) ^ ((r & 7) << 3);
        aF[f] = *(const bf16x8*)(lA + r * 64 + ce);
      }
#pragma unroll
      for (int f = 0; f < 8; ++f) {
        int r = wn * 128 + f * 16 + (l & 15);
        int ce = (kc * 32 + ((l >> 4) << 3)) ^ ((r & 7) << 3);
        bF[f] = *(const bf16x8*)(lB + r * 64 + ce);
      }
#pragma unroll
      for (int mf = 0; mf < 4; ++mf)
#pragma unroll
        for (int nf = 0; nf < 8; ++nf)
          acc[mf][nf] = __builtin_amdgcn_mfma_f32_16x16x32_bf16(
              aF[mf], bF[nf], acc[mf][nf], 0, 0, 0);
    }
    __syncthreads();
  }

  const int lr = (l >> 4) << 2, lc = l & 15;
  // pass 1: v = acc + bias + resid -> xout; row partial sums
#pragma unroll
  for (int mf = 0; mf < 4; ++mf) {
#pragma unroll
    for (int jj = 0; jj < 4; ++jj) {
      int rowl = wm * 64 + mf * 16 + lr + jj;
      int row = m0 + rowl;
      float s = 0.f, q = 0.f;
#pragma unroll
      for (int nf = 0; nf < 8; ++nf) {
        int col = wn * 128 + nf * 16 + lc;
        float v = acc[mf][nf][jj] + bias[col] + resid[(size_t)row * 256 + col];
        acc[mf][nf][jj] = v;
        xout[(size_t)row * 256 + col] = v;
        s += v;
        q += v * v;
      }
#pragma unroll
      for (int off = 1; off < 16; off <<= 1) {
        s += __shfl_xor(s, off);
        q += __shfl_xor(q, off);
      }
      if (lc == 0) {
        psum[wn][rowl] = s;
        psq[wn][rowl] = q;
      }
    }
  }
  __syncthreads();
  // pass 2: LN -> act bf16
#pragma unroll
  for (int mf = 0; mf < 4; ++mf) {
#pragma unroll
    for (int jj = 0; jj < 4; ++jj) {
      int rowl = wm * 64 + mf * 16 + lr + jj;
      int row = m0 + rowl;
      float S = psum[0][rowl] + psum[1][rowl];
      float Q = psq[0][rowl] + psq[1][rowl];
      float mean = S * (1.0f / 256.0f);
      float var = Q * (1.0f / 256.0f) - mean * mean;
      float rstd = rsqrtf(var + 1e-5f);
#pragma unroll
      for (int nf = 0; nf < 8; ++nf) {
        int col = wn * 128 + nf * 16 + lc;
        float v = (acc[mf][nf][jj] - mean) * rstd * lng[col] + lnb[col];
        act[(size_t)row * 256 + col] = (short)f2bf(v);
      }
    }
  }
}

extern "C" void kernel_launch(void* const* d_in, const int* in_sizes, int n_in,
                              void* d_out, int out_size, void* d_ws, size_t ws_size,
                              hipStream_t stream) {
  const float* in_x   = (const float*)d_in[0];
  const int*   knn    = (const int*)d_in[1];
  const float* ln1_g  = (const float*)d_in[2];
  const float* ln1_b  = (const float*)d_in[3];
  const float* w_qkv  = (const float*)d_in[4];
  const float* w_proj = (const float*)d_in[5];
  const float* b_proj = (const float*)d_in[6];
  const float* ln2_g  = (const float*)d_in[7];
  const float* ln2_b  = (const float*)d_in[8];
  const float* w_fc1  = (const float*)d_in[9];
  const float* b_fc1  = (const float*)d_in[10];
  const float* w_fc2  = (const float*)d_in[11];
  const float* b_fc2  = (const float*)d_in[12];

  // Workspace layout (total 230.3 MB — matches the R2 footprint that fit):
  //   x    [0,   64) MB   f32 [N][256]
  //   act  [64,  96) MB   bf16 [N][256] (LN output)
  //   big  [96, 224) MB   bf16 [N][1024] (fc1 out); sub-aliases during attn:
  //     q_bf [96,128)  k8 [128,144)  v8 [144,160)  attb [160,192)
  //   wT   [224, 230.3) MB  transposed bf16 weights
  char* ws = (char*)d_ws;
  float* x    = (float*)(ws);
  short* act  = (short*)(ws + 67108864);
  short* big  = (short*)(ws + 100663296);
  short* q_bf = big;
  uchar* k8   = (uchar*)(ws + 134217728);
  uchar* v8   = (uchar*)(ws + 150994944);
  short* attb = (short*)(ws + 167772160);
  short* wT   = (short*)(ws + 234881024);
  short* wqkvT  = wT;                // [L][768][256]
  short* wprojT = wT + 786432;       // [L][256][256]
  short* wfc1T  = wT + 1048576;      // [L][1024][256]
  short* wfc2T  = wT + 2097152;      // [L][256][1024]

  wcast<<<dim3(768, 4), 256, 0, stream>>>(w_qkv, wqkvT, 256, 768);
  wcast<<<dim3(256, 4), 256, 0, stream>>>(w_proj, wprojT, 256, 256);
  wcast<<<dim3(1024, 4), 256, 0, stream>>>(w_fc1, wfc1T, 256, 1024);
  wcast<<<dim3(1024, 4), 256, 0, stream>>>(w_fc2, wfc2T, 1024, 256);

  ln_k<<<16384, 256, 0, stream>>>(in_x, ln1_g, ln1_b, act);

  for (int i = 0; i < 4; ++i) {
    const float* xin = (i == 0) ? in_x : x;
    int inext = (i < 3) ? i + 1 : 3;
    gemm_k<3, 256><<<3072, 256, 0, stream>>>(
        act, wqkvT + (size_t)i * 196608, nullptr, q_bf, k8, v8, 768, 6);
    attn_k<<<16384, 256, 0, stream>>>(q_bf, k8, v8, knn, attb);
    gemm_ln<256><<<512, 256, 0, stream>>>(
        attb, wprojT + (size_t)i * 65536, b_proj + i * 256, xin, x,
        ln2_g + i * 256, ln2_b + i * 256, act);
    gemm_k<2, 256><<<4096, 256, 0, stream>>>(
        act, wfc1T + (size_t)i * 262144, b_fc1 + i * 1024, big,
        nullptr, nullptr, 1024, 8);
    gemm_ln<1024><<<512, 256, 0, stream>>>(
        big, wfc2T + (size_t)i * 262144, b_fc2 + i * 256, x,
        (i == 3) ? (float*)d_out : x,
        ln1_g + inext * 256, ln1_b + inext * 256, act);
  }
}

// Round 6
// 1589.445 us; speedup vs baseline: 1.0730x; 1.0730x over previous
//
#include <hip/hip_runtime.h>

typedef __attribute__((ext_vector_type(4))) float  f32x4;
typedef __attribute__((ext_vector_type(2))) float  f32x2;
typedef __attribute__((ext_vector_type(8))) __bf16 bf16x8;
typedef __attribute__((ext_vector_type(4))) short  s16x4;
typedef __attribute__((ext_vector_type(8))) short  s16x8;
typedef unsigned char uchar;

__device__ __forceinline__ unsigned short f2bf(float f) {
  unsigned u = __builtin_bit_cast(unsigned, f);
  u += 0x7FFFu + ((u >> 16) & 1u);
  return (unsigned short)(u >> 16);
}
__device__ __forceinline__ float b2f(short s) {
  return __builtin_bit_cast(float, (unsigned)((unsigned short)s) << 16);
}
__device__ __forceinline__ uchar f2fp8(float v) {
  return (uchar)(__builtin_amdgcn_cvt_pk_fp8_f32(v, v, 0, false) & 0xFF);
}
__device__ __forceinline__ float gelu_fast(float v) {
  float u = v * (0.7978845608f + 0.0356774081f * v * v);
  float t = __expf(-2.f * fabsf(u));
  float th = (1.f - t) / (1.f + t);
  th = (u >= 0.f) ? th : -th;
  return 0.5f * v * (1.f + th);
}

__device__ __forceinline__ void gload16(const void* g, void* l) {
  __builtin_amdgcn_global_load_lds(
      (const __attribute__((address_space(1))) void*)g,
      (__attribute__((address_space(3))) void*)l, 16, 0, 0);
}

// Transpose + cast weights: W [L][In][Out] f32 -> WT [L][Out][In] bf16
__global__ __launch_bounds__(256) void wcast(const float* __restrict__ W,
                                             short* __restrict__ WT,
                                             int In, int Out) {
  int i = blockIdx.x * 256 + threadIdx.x;
  int lay = blockIdx.y;
  if (i >= In * Out) return;
  const float* w = W + (size_t)lay * In * Out;
  short* wt = WT + (size_t)lay * In * Out;
  int ii = i % In, oo = i / In;
  wt[(size_t)oo * In + ii] = (short)f2bf(w[(size_t)ii * Out + oo]);
}

// LayerNorm over C=256, one wave per row, write bf16 (used once, on in_x)
__global__ __launch_bounds__(256) void ln_k(const float* __restrict__ x,
                                            const float* __restrict__ g,
                                            const float* __restrict__ b,
                                            short* __restrict__ out) {
  int row = blockIdx.x * 4 + (threadIdx.x >> 6);
  int l = threadIdx.x & 63;
  const float4 v = *(const float4*)(x + (size_t)row * 256 + l * 4);
  float s  = v.x + v.y + v.z + v.w;
  float ss = v.x * v.x + v.y * v.y + v.z * v.z + v.w * v.w;
#pragma unroll
  for (int o = 32; o >= 1; o >>= 1) {
    s  += __shfl_xor(s, o);
    ss += __shfl_xor(ss, o);
  }
  float mean = s * (1.0f / 256.0f);
  float var  = ss * (1.0f / 256.0f) - mean * mean;
  float rstd = rsqrtf(var + 1e-5f);
  const float4 gg = *(const float4*)(g + l * 4);
  const float4 bb = *(const float4*)(b + l * 4);
  s16x4 o4;
  o4[0] = (short)f2bf((v.x - mean) * rstd * gg.x + bb.x);
  o4[1] = (short)f2bf((v.y - mean) * rstd * gg.y + bb.y);
  o4[2] = (short)f2bf((v.z - mean) * rstd * gg.z + bb.z);
  o4[3] = (short)f2bf((v.w - mean) * rstd * gg.w + bb.w);
  *(s16x4*)(out + (size_t)row * 256 + l * 4) = o4;
}

// KNN attention: one wave per point. q bf16 [N][256], k8/v8 fp8 [N][256]
__global__ __launch_bounds__(256) void attn_k(const short* __restrict__ q_,
                                              const uchar* __restrict__ k8,
                                              const uchar* __restrict__ v8,
                                              const int* __restrict__ knn,
                                              short* __restrict__ out) {
  int n = blockIdx.x * 4 + (threadIdx.x >> 6);
  int l = threadIdx.x & 63;
  int j = l & 15, g = l >> 4;
  int idxj = knn[(size_t)n * 16 + j];
  const short* qp = q_ + (size_t)n * 256 + g * 64;
  const uchar* kp = k8 + (size_t)idxj * 256 + g * 64;
  float partial = 0.f;
#pragma unroll
  for (int t = 0; t < 4; ++t) {  // 16 channels per t
    int4 kv = *(const int4*)(kp + t * 16);
    s16x8 q0 = *(const s16x8*)(qp + t * 16);
    s16x8 q1 = *(const s16x8*)(qp + t * 16 + 8);
    f32x2 a;
    a = __builtin_amdgcn_cvt_pk_f32_fp8(kv.x, false);
    partial += a[0] * b2f(q0[0]) + a[1] * b2f(q0[1]);
    a = __builtin_amdgcn_cvt_pk_f32_fp8(kv.x, true);
    partial += a[0] * b2f(q0[2]) + a[1] * b2f(q0[3]);
    a = __builtin_amdgcn_cvt_pk_f32_fp8(kv.y, false);
    partial += a[0] * b2f(q0[4]) + a[1] * b2f(q0[5]);
    a = __builtin_amdgcn_cvt_pk_f32_fp8(kv.y, true);
    partial += a[0] * b2f(q0[6]) + a[1] * b2f(q0[7]);
    a = __builtin_amdgcn_cvt_pk_f32_fp8(kv.z, false);
    partial += a[0] * b2f(q1[0]) + a[1] * b2f(q1[1]);
    a = __builtin_amdgcn_cvt_pk_f32_fp8(kv.z, true);
    partial += a[0] * b2f(q1[2]) + a[1] * b2f(q1[3]);
    a = __builtin_amdgcn_cvt_pk_f32_fp8(kv.w, false);
    partial += a[0] * b2f(q1[4]) + a[1] * b2f(q1[5]);
    a = __builtin_amdgcn_cvt_pk_f32_fp8(kv.w, true);
    partial += a[0] * b2f(q1[6]) + a[1] * b2f(q1[7]);
  }
  partial += __shfl_xor(partial, 16);
  partial += __shfl_xor(partial, 32);
  float score = partial * 0.0625f;  // C^-0.5, C=256
  float mx = score;
#pragma unroll
  for (int o = 1; o < 16; o <<= 1) mx = fmaxf(mx, __shfl_xor(mx, o));
  float e = __expf(score - mx);
  float sum = e;
#pragma unroll
  for (int o = 1; o < 16; o <<= 1) sum += __shfl_xor(sum, o);
  float attn = e / sum;
  float4 o4 = {0.f, 0.f, 0.f, 0.f};
#pragma unroll
  for (int jj = 0; jj < 16; ++jj) {
    float aj = __shfl(attn, jj);
    int   ij = __shfl(idxj, jj);
    int vv = *(const int*)(v8 + (size_t)ij * 256 + l * 4);
    f32x2 lo = __builtin_amdgcn_cvt_pk_f32_fp8(vv, false);
    f32x2 hi = __builtin_amdgcn_cvt_pk_f32_fp8(vv, true);
    o4.x += aj * lo[0];
    o4.y += aj * lo[1];
    o4.z += aj * hi[0];
    o4.w += aj * hi[1];
  }
  s16x4 ob;
  ob[0] = (short)f2bf(o4.x);
  ob[1] = (short)f2bf(o4.y);
  ob[2] = (short)f2bf(o4.z);
  ob[3] = (short)f2bf(o4.w);
  *(s16x4*)(out + (size_t)n * 256 + l * 4) = ob;
}

// GEMM: A [M][KD] bf16 x BT [Nout][KD] bf16 -> out [M][Nout]
// EPI 2: +bias, fast-gelu -> bf16. EPI 3: qkv split -> q bf16 / k8 / v8 fp8.
// 128x128 tile, BK=64, 4 waves (2x2), T2 XOR swizzle, T1 XCD-chunked swizzle.
template <int EPI, int KD>
__global__ __launch_bounds__(256) void gemm_k(
    const short* __restrict__ A, const short* __restrict__ BT,
    const float* __restrict__ bias, short* __restrict__ outb,
    uchar* __restrict__ k8, uchar* __restrict__ v8, int Nout, int gx) {
  __shared__ __align__(16) short lA[128 * 64];
  __shared__ __align__(16) short lB[128 * 64];
  const int tid = threadIdx.x;
  const int l = tid & 63, w = tid >> 6;
  const int nwg = gridDim.x;
  const int bid = blockIdx.x;
  const int swz = (bid & 7) * (nwg >> 3) + (bid >> 3);
  const int m0 = (swz / gx) << 7, n0 = (swz % gx) << 7;
  const int wm = w >> 1, wn = w & 1;

  f32x4 acc[4][4];
#pragma unroll
  for (int i = 0; i < 4; ++i)
#pragma unroll
    for (int jj = 0; jj < 4; ++jj) acc[i][jj] = f32x4{0.f, 0.f, 0.f, 0.f};

  const int srow = (w << 3) + (l >> 3);
  const int scol = (((l & 7) << 3)) ^ ((srow & 7) << 3);
  const short* gA = A + (size_t)(m0 + srow) * KD + scol;
  const short* gB = BT + (size_t)(n0 + srow) * KD + scol;

  for (int kt = 0; kt < KD; kt += 64) {
#pragma unroll
    for (int it = 0; it < 4; ++it) {
      gload16(gA + (size_t)(it * 32) * KD + kt, &lA[(it * 32 + w * 8) * 64]);
      gload16(gB + (size_t)(it * 32) * KD + kt, &lB[(it * 32 + w * 8) * 64]);
    }
    __syncthreads();
#pragma unroll
    for (int kc = 0; kc < 2; ++kc) {
      bf16x8 aF[4], bF[4];
#pragma unroll
      for (int f = 0; f < 4; ++f) {
        int r = wm * 64 + f * 16 + (l & 15);
        int ce = (kc * 32 + ((l >> 4) << 3)) ^ ((r & 7) << 3);
        aF[f] = *(const bf16x8*)(lA + r * 64 + ce);
      }
#pragma unroll
      for (int f = 0; f < 4; ++f) {
        int r = wn * 64 + f * 16 + (l & 15);
        int ce = (kc * 32 + ((l >> 4) << 3)) ^ ((r & 7) << 3);
        bF[f] = *(const bf16x8*)(lB + r * 64 + ce);
      }
#pragma unroll
      for (int mf = 0; mf < 4; ++mf)
#pragma unroll
        for (int nf = 0; nf < 4; ++nf)
          acc[mf][nf] = __builtin_amdgcn_mfma_f32_16x16x32_bf16(
              aF[mf], bF[nf], acc[mf][nf], 0, 0, 0);
    }
    __syncthreads();
  }

  const int lr = (l >> 4) << 2, lc = l & 15;
#pragma unroll
  for (int mf = 0; mf < 4; ++mf) {
#pragma unroll
    for (int nf = 0; nf < 4; ++nf) {
#pragma unroll
      for (int jj = 0; jj < 4; ++jj) {
        int row = m0 + wm * 64 + mf * 16 + lr + jj;
        int col = n0 + wn * 64 + nf * 16 + lc;
        float v = acc[mf][nf][jj];
        if (EPI == 2) {
          v = gelu_fast(v + bias[col]);
          outb[(size_t)row * Nout + col] = (short)f2bf(v);
        } else {  // EPI 3: qkv split
          if (col < 256)
            outb[(size_t)row * 256 + col] = (short)f2bf(v);
          else if (col < 512)
            k8[(size_t)row * 256 + (col - 256)] = f2fp8(v);
          else
            v8[(size_t)row * 256 + (col - 512)] = f2fp8(v);
        }
      }
    }
  }
}

// GEMM + bias + residual + fused LayerNorm.  v2: 64-row x 256-col tile.
// 4 waves; wave w owns cols [w*64, w*64+64) of all 64 rows -> acc[4][4].
// A [M][KD] bf16 x BT [256][KD] bf16; xout f32 [M][256]; act = LN bf16.
template <int KD>
__global__ __launch_bounds__(256) void gemm_ln(
    const short* __restrict__ A, const short* __restrict__ BT,
    const float* __restrict__ bias, const float* __restrict__ resid,
    float* __restrict__ xout, const float* __restrict__ lng,
    const float* __restrict__ lnb, short* __restrict__ act) {
  __shared__ __align__(16) short lA[64 * 64];
  __shared__ __align__(16) short lB[256 * 64];
  __shared__ float psum[4][64], psq[4][64];
  const int tid = threadIdx.x;
  const int l = tid & 63, w = tid >> 6;
  const int nwg = gridDim.x;  // 1024
  const int bid = blockIdx.x;
  const int swz = (bid & 7) * (nwg >> 3) + (bid >> 3);
  const int m0 = swz << 6;

  f32x4 acc[4][4];
#pragma unroll
  for (int i = 0; i < 4; ++i)
#pragma unroll
    for (int jj = 0; jj < 4; ++jj) acc[i][jj] = f32x4{0.f, 0.f, 0.f, 0.f};

  const int srow = (w << 3) + (l >> 3);                   // 0..31
  const int scol = (((l & 7) << 3)) ^ ((srow & 7) << 3);  // swizzled src col
  const short* gA = A + (size_t)(m0 + srow) * KD + scol;
  const short* gB = BT + (size_t)srow * KD + scol;

  for (int kt = 0; kt < KD; kt += 64) {
#pragma unroll
    for (int it = 0; it < 2; ++it)
      gload16(gA + (size_t)(it * 32) * KD + kt, &lA[(it * 32 + w * 8) * 64]);
#pragma unroll
    for (int it = 0; it < 8; ++it)
      gload16(gB + (size_t)(it * 32) * KD + kt, &lB[(it * 32 + w * 8) * 64]);
    __syncthreads();
#pragma unroll
    for (int kc = 0; kc < 2; ++kc) {
      bf16x8 aF[4], bF[4];
#pragma unroll
      for (int f = 0; f < 4; ++f) {
        int r = f * 16 + (l & 15);
        int ce = (kc * 32 + ((l >> 4) << 3)) ^ ((r & 7) << 3);
        aF[f] = *(const bf16x8*)(lA + r * 64 + ce);
      }
#pragma unroll
      for (int f = 0; f < 4; ++f) {
        int r = w * 64 + f * 16 + (l & 15);
        int ce = (kc * 32 + ((l >> 4) << 3)) ^ ((r & 7) << 3);
        bF[f] = *(const bf16x8*)(lB + r * 64 + ce);
      }
#pragma unroll
      for (int mf = 0; mf < 4; ++mf)
#pragma unroll
        for (int nf = 0; nf < 4; ++nf)
          acc[mf][nf] = __builtin_amdgcn_mfma_f32_16x16x32_bf16(
              aF[mf], bF[nf], acc[mf][nf], 0, 0, 0);
    }
    __syncthreads();
  }

  const int lr = (l >> 4) << 2, lc = l & 15;
  // pass 1: v = acc + bias + resid -> xout; per-wave row partial sums
#pragma unroll
  for (int mf = 0; mf < 4; ++mf) {
#pragma unroll
    for (int jj = 0; jj < 4; ++jj) {
      int rowl = mf * 16 + lr + jj;
      int row = m0 + rowl;
      float s = 0.f, q = 0.f;
#pragma unroll
      for (int nf = 0; nf < 4; ++nf) {
        int col = w * 64 + nf * 16 + lc;
        float v = acc[mf][nf][jj] + bias[col] + resid[(size_t)row * 256 + col];
        acc[mf][nf][jj] = v;
        xout[(size_t)row * 256 + col] = v;
        s += v;
        q += v * v;
      }
#pragma unroll
      for (int off = 1; off < 16; off <<= 1) {
        s += __shfl_xor(s, off);
        q += __shfl_xor(q, off);
      }
      if (lc == 0) {
        psum[w][rowl] = s;
        psq[w][rowl] = q;
      }
    }
  }
  __syncthreads();
  // pass 2: LN -> act bf16
#pragma unroll
  for (int mf = 0; mf < 4; ++mf) {
#pragma unroll
    for (int jj = 0; jj < 4; ++jj) {
      int rowl = mf * 16 + lr + jj;
      int row = m0 + rowl;
      float S = psum[0][rowl] + psum[1][rowl] + psum[2][rowl] + psum[3][rowl];
      float Q = psq[0][rowl] + psq[1][rowl] + psq[2][rowl] + psq[3][rowl];
      float mean = S * (1.0f / 256.0f);
      float var = Q * (1.0f / 256.0f) - mean * mean;
      float rstd = rsqrtf(var + 1e-5f);
#pragma unroll
      for (int nf = 0; nf < 4; ++nf) {
        int col = w * 64 + nf * 16 + lc;
        float v = (acc[mf][nf][jj] - mean) * rstd * lng[col] + lnb[col];
        act[(size_t)row * 256 + col] = (short)f2bf(v);
      }
    }
  }
}

extern "C" void kernel_launch(void* const* d_in, const int* in_sizes, int n_in,
                              void* d_out, int out_size, void* d_ws, size_t ws_size,
                              hipStream_t stream) {
  const float* in_x   = (const float*)d_in[0];
  const int*   knn    = (const int*)d_in[1];
  const float* ln1_g  = (const float*)d_in[2];
  const float* ln1_b  = (const float*)d_in[3];
  const float* w_qkv  = (const float*)d_in[4];
  const float* w_proj = (const float*)d_in[5];
  const float* b_proj = (const float*)d_in[6];
  const float* ln2_g  = (const float*)d_in[7];
  const float* ln2_b  = (const float*)d_in[8];
  const float* w_fc1  = (const float*)d_in[9];
  const float* b_fc1  = (const float*)d_in[10];
  const float* w_fc2  = (const float*)d_in[11];
  const float* b_fc2  = (const float*)d_in[12];

  // Workspace layout (total 230.3 MB):
  //   x    [0,   64) MB   f32 [N][256]
  //   act  [64,  96) MB   bf16 [N][256] (LN output)
  //   big  [96, 224) MB   bf16 [N][1024] (fc1 out); sub-aliases during attn:
  //     q_bf [96,128)  k8 [128,144)  v8 [144,160)  attb [160,192)
  //   wT   [224, 230.3) MB  transposed bf16 weights
  char* ws = (char*)d_ws;
  float* x    = (float*)(ws);
  short* act  = (short*)(ws + 67108864);
  short* big  = (short*)(ws + 100663296);
  short* q_bf = big;
  uchar* k8   = (uchar*)(ws + 134217728);
  uchar* v8   = (uchar*)(ws + 150994944);
  short* attb = (short*)(ws + 167772160);
  short* wT   = (short*)(ws + 234881024);
  short* wqkvT  = wT;                // [L][768][256]
  short* wprojT = wT + 786432;       // [L][256][256]
  short* wfc1T  = wT + 1048576;      // [L][1024][256]
  short* wfc2T  = wT + 2097152;      // [L][256][1024]

  wcast<<<dim3(768, 4), 256, 0, stream>>>(w_qkv, wqkvT, 256, 768);
  wcast<<<dim3(256, 4), 256, 0, stream>>>(w_proj, wprojT, 256, 256);
  wcast<<<dim3(1024, 4), 256, 0, stream>>>(w_fc1, wfc1T, 256, 1024);
  wcast<<<dim3(1024, 4), 256, 0, stream>>>(w_fc2, wfc2T, 1024, 256);

  ln_k<<<16384, 256, 0, stream>>>(in_x, ln1_g, ln1_b, act);

  for (int i = 0; i < 4; ++i) {
    const float* xin = (i == 0) ? in_x : x;
    int inext = (i < 3) ? i + 1 : 3;
    gemm_k<3, 256><<<3072, 256, 0, stream>>>(
        act, wqkvT + (size_t)i * 196608, nullptr, q_bf, k8, v8, 768, 6);
    attn_k<<<16384, 256, 0, stream>>>(q_bf, k8, v8, knn, attb);
    gemm_ln<256><<<1024, 256, 0, stream>>>(
        attb, wprojT + (size_t)i * 65536, b_proj + i * 256, xin, x,
        ln2_g + i * 256, ln2_b + i * 256, act);
    gemm_k<2, 256><<<4096, 256, 0, stream>>>(
        act, wfc1T + (size_t)i * 262144, b_fc1 + i * 1024, big,
        nullptr, nullptr, 1024, 8);
    gemm_ln<1024><<<1024, 256, 0, stream>>>(
        big, wfc2T + (size_t)i * 262144, b_fc2 + i * 256, x,
        (i == 3) ? (float*)d_out : x,
        ln1_g + inext * 256, ln1_b + inext * 256, act);
  }
}

// Round 7
// 1304.079 us; speedup vs baseline: 1.3078x; 1.2188x over previous
//
#include <hip/hip_runtime.h>

typedef __attribute__((ext_vector_type(4))) float  f32x4;
typedef __attribute__((ext_vector_type(2))) float  f32x2;
typedef __attribute__((ext_vector_type(8))) __bf16 bf16x8;
typedef __attribute__((ext_vector_type(4))) short  s16x4;
typedef __attribute__((ext_vector_type(8))) short  s16x8;
typedef unsigned char uchar;

__device__ __forceinline__ unsigned short f2bf(float f) {
  unsigned u = __builtin_bit_cast(unsigned, f);
  u += 0x7FFFu + ((u >> 16) & 1u);
  return (unsigned short)(u >> 16);
}
__device__ __forceinline__ float b2f(short s) {
  return __builtin_bit_cast(float, (unsigned)((unsigned short)s) << 16);
}
__device__ __forceinline__ uchar f2fp8(float v) {
  return (uchar)(__builtin_amdgcn_cvt_pk_fp8_f32(v, v, 0, false) & 0xFF);
}
__device__ __forceinline__ float gelu_fast(float v) {
  float u = v * (0.7978845608f + 0.0356774081f * v * v);
  float t = __expf(-2.f * fabsf(u));
  float th = (1.f - t) / (1.f + t);
  th = (u >= 0.f) ? th : -th;
  return 0.5f * v * (1.f + th);
}

__device__ __forceinline__ void gload16(const void* g, void* l) {
  __builtin_amdgcn_global_load_lds(
      (const __attribute__((address_space(1))) void*)g,
      (__attribute__((address_space(3))) void*)l, 16, 0, 0);
}

// Transpose + cast weights: W [L][In][Out] f32 -> WT [L][Out][In] bf16
__global__ __launch_bounds__(256) void wcast(const float* __restrict__ W,
                                             short* __restrict__ WT,
                                             int In, int Out) {
  int i = blockIdx.x * 256 + threadIdx.x;
  int lay = blockIdx.y;
  if (i >= In * Out) return;
  const float* w = W + (size_t)lay * In * Out;
  short* wt = WT + (size_t)lay * In * Out;
  int ii = i % In, oo = i / In;
  wt[(size_t)oo * In + ii] = (short)f2bf(w[(size_t)ii * Out + oo]);
}

// LayerNorm over C=256, one wave per row, write bf16
__global__ __launch_bounds__(256) void ln_k(const float* __restrict__ x,
                                            const float* __restrict__ g,
                                            const float* __restrict__ b,
                                            short* __restrict__ out) {
  int row = blockIdx.x * 4 + (threadIdx.x >> 6);
  int l = threadIdx.x & 63;
  const float4 v = *(const float4*)(x + (size_t)row * 256 + l * 4);
  float s  = v.x + v.y + v.z + v.w;
  float ss = v.x * v.x + v.y * v.y + v.z * v.z + v.w * v.w;
#pragma unroll
  for (int o = 32; o >= 1; o >>= 1) {
    s  += __shfl_xor(s, o);
    ss += __shfl_xor(ss, o);
  }
  float mean = s * (1.0f / 256.0f);
  float var  = ss * (1.0f / 256.0f) - mean * mean;
  float rstd = rsqrtf(var + 1e-5f);
  const float4 gg = *(const float4*)(g + l * 4);
  const float4 bb = *(const float4*)(b + l * 4);
  s16x4 o4;
  o4[0] = (short)f2bf((v.x - mean) * rstd * gg.x + bb.x);
  o4[1] = (short)f2bf((v.y - mean) * rstd * gg.y + bb.y);
  o4[2] = (short)f2bf((v.z - mean) * rstd * gg.z + bb.z);
  o4[3] = (short)f2bf((v.w - mean) * rstd * gg.w + bb.w);
  *(s16x4*)(out + (size_t)row * 256 + l * 4) = o4;
}

// KNN attention: one wave per point. q bf16 [N][256], k8/v8 fp8 [N][256]
__global__ __launch_bounds__(256) void attn_k(const short* __restrict__ q_,
                                              const uchar* __restrict__ k8,
                                              const uchar* __restrict__ v8,
                                              const int* __restrict__ knn,
                                              short* __restrict__ out) {
  int n = blockIdx.x * 4 + (threadIdx.x >> 6);
  int l = threadIdx.x & 63;
  int j = l & 15, g = l >> 4;
  int idxj = knn[(size_t)n * 16 + j];
  const short* qp = q_ + (size_t)n * 256 + g * 64;
  const uchar* kp = k8 + (size_t)idxj * 256 + g * 64;
  float partial = 0.f;
#pragma unroll
  for (int t = 0; t < 4; ++t) {  // 16 channels per t
    int4 kv = *(const int4*)(kp + t * 16);
    s16x8 q0 = *(const s16x8*)(qp + t * 16);
    s16x8 q1 = *(const s16x8*)(qp + t * 16 + 8);
    f32x2 a;
    a = __builtin_amdgcn_cvt_pk_f32_fp8(kv.x, false);
    partial += a[0] * b2f(q0[0]) + a[1] * b2f(q0[1]);
    a = __builtin_amdgcn_cvt_pk_f32_fp8(kv.x, true);
    partial += a[0] * b2f(q0[2]) + a[1] * b2f(q0[3]);
    a = __builtin_amdgcn_cvt_pk_f32_fp8(kv.y, false);
    partial += a[0] * b2f(q0[4]) + a[1] * b2f(q0[5]);
    a = __builtin_amdgcn_cvt_pk_f32_fp8(kv.y, true);
    partial += a[0] * b2f(q0[6]) + a[1] * b2f(q0[7]);
    a = __builtin_amdgcn_cvt_pk_f32_fp8(kv.z, false);
    partial += a[0] * b2f(q1[0]) + a[1] * b2f(q1[1]);
    a = __builtin_amdgcn_cvt_pk_f32_fp8(kv.z, true);
    partial += a[0] * b2f(q1[2]) + a[1] * b2f(q1[3]);
    a = __builtin_amdgcn_cvt_pk_f32_fp8(kv.w, false);
    partial += a[0] * b2f(q1[4]) + a[1] * b2f(q1[5]);
    a = __builtin_amdgcn_cvt_pk_f32_fp8(kv.w, true);
    partial += a[0] * b2f(q1[6]) + a[1] * b2f(q1[7]);
  }
  partial += __shfl_xor(partial, 16);
  partial += __shfl_xor(partial, 32);
  float score = partial * 0.0625f;  // C^-0.5, C=256
  float mx = score;
#pragma unroll
  for (int o = 1; o < 16; o <<= 1) mx = fmaxf(mx, __shfl_xor(mx, o));
  float e = __expf(score - mx);
  float sum = e;
#pragma unroll
  for (int o = 1; o < 16; o <<= 1) sum += __shfl_xor(sum, o);
  float attn = e / sum;
  float4 o4 = {0.f, 0.f, 0.f, 0.f};
#pragma unroll
  for (int jj = 0; jj < 16; ++jj) {
    float aj = __shfl(attn, jj);
    int   ij = __shfl(idxj, jj);
    int vv = *(const int*)(v8 + (size_t)ij * 256 + l * 4);
    f32x2 lo = __builtin_amdgcn_cvt_pk_f32_fp8(vv, false);
    f32x2 hi = __builtin_amdgcn_cvt_pk_f32_fp8(vv, true);
    o4.x += aj * lo[0];
    o4.y += aj * lo[1];
    o4.z += aj * hi[0];
    o4.w += aj * hi[1];
  }
  s16x4 ob;
  ob[0] = (short)f2bf(o4.x);
  ob[1] = (short)f2bf(o4.y);
  ob[2] = (short)f2bf(o4.z);
  ob[3] = (short)f2bf(o4.w);
  *(s16x4*)(out + (size_t)n * 256 + l * 4) = ob;
}

// GEMM: A [M][KD] bf16 x BT [Nout][KD] bf16 -> out [M][Nout]
// EPI 1: +bias +resid(f32) -> f32.  EPI 2: +bias, fast-gelu -> bf16.
// EPI 3: qkv split -> q bf16 / k8 fp8 / v8 fp8.
// 128x128 tile, BK=64, 4 waves (2x2), T2 XOR swizzle, T1 XCD-chunked swizzle.
template <int EPI, int KD>
__global__ __launch_bounds__(256) void gemm_k(
    const short* __restrict__ A, const short* __restrict__ BT,
    const float* __restrict__ bias, const float* __restrict__ resid,
    short* __restrict__ outb, float* __restrict__ outf,
    uchar* __restrict__ k8, uchar* __restrict__ v8, int Nout, int gx) {
  __shared__ __align__(16) short lA[128 * 64];
  __shared__ __align__(16) short lB[128 * 64];
  const int tid = threadIdx.x;
  const int l = tid & 63, w = tid >> 6;
  const int nwg = gridDim.x;
  const int bid = blockIdx.x;
  const int swz = (bid & 7) * (nwg >> 3) + (bid >> 3);
  const int m0 = (swz / gx) << 7, n0 = (swz % gx) << 7;
  const int wm = w >> 1, wn = w & 1;

  f32x4 acc[4][4];
#pragma unroll
  for (int i = 0; i < 4; ++i)
#pragma unroll
    for (int jj = 0; jj < 4; ++jj) acc[i][jj] = f32x4{0.f, 0.f, 0.f, 0.f};

  const int srow = (w << 3) + (l >> 3);
  const int scol = (((l & 7) << 3)) ^ ((srow & 7) << 3);
  const short* gA = A + (size_t)(m0 + srow) * KD + scol;
  const short* gB = BT + (size_t)(n0 + srow) * KD + scol;

  for (int kt = 0; kt < KD; kt += 64) {
#pragma unroll
    for (int it = 0; it < 4; ++it) {
      gload16(gA + (size_t)(it * 32) * KD + kt, &lA[(it * 32 + w * 8) * 64]);
      gload16(gB + (size_t)(it * 32) * KD + kt, &lB[(it * 32 + w * 8) * 64]);
    }
    __syncthreads();
#pragma unroll
    for (int kc = 0; kc < 2; ++kc) {
      bf16x8 aF[4], bF[4];
#pragma unroll
      for (int f = 0; f < 4; ++f) {
        int r = wm * 64 + f * 16 + (l & 15);
        int ce = (kc * 32 + ((l >> 4) << 3)) ^ ((r & 7) << 3);
        aF[f] = *(const bf16x8*)(lA + r * 64 + ce);
      }
#pragma unroll
      for (int f = 0; f < 4; ++f) {
        int r = wn * 64 + f * 16 + (l & 15);
        int ce = (kc * 32 + ((l >> 4) << 3)) ^ ((r & 7) << 3);
        bF[f] = *(const bf16x8*)(lB + r * 64 + ce);
      }
#pragma unroll
      for (int mf = 0; mf < 4; ++mf)
#pragma unroll
        for (int nf = 0; nf < 4; ++nf)
          acc[mf][nf] = __builtin_amdgcn_mfma_f32_16x16x32_bf16(
              aF[mf], bF[nf], acc[mf][nf], 0, 0, 0);
    }
    __syncthreads();
  }

  const int lr = (l >> 4) << 2, lc = l & 15;
#pragma unroll
  for (int mf = 0; mf < 4; ++mf) {
#pragma unroll
    for (int nf = 0; nf < 4; ++nf) {
#pragma unroll
      for (int jj = 0; jj < 4; ++jj) {
        int row = m0 + wm * 64 + mf * 16 + lr + jj;
        int col = n0 + wn * 64 + nf * 16 + lc;
        float v = acc[mf][nf][jj];
        if (EPI == 1) {
          v += bias[col] + resid[(size_t)row * 256 + col];
          outf[(size_t)row * 256 + col] = v;
        } else if (EPI == 2) {
          v = gelu_fast(v + bias[col]);
          outb[(size_t)row * Nout + col] = (short)f2bf(v);
        } else {  // EPI 3: qkv split
          if (col < 256)
            outb[(size_t)row * 256 + col] = (short)f2bf(v);
          else if (col < 512)
            k8[(size_t)row * 256 + (col - 256)] = f2fp8(v);
          else
            v8[(size_t)row * 256 + (col - 512)] = f2fp8(v);
        }
      }
    }
  }
}

extern "C" void kernel_launch(void* const* d_in, const int* in_sizes, int n_in,
                              void* d_out, int out_size, void* d_ws, size_t ws_size,
                              hipStream_t stream) {
  const float* in_x   = (const float*)d_in[0];
  const int*   knn    = (const int*)d_in[1];
  const float* ln1_g  = (const float*)d_in[2];
  const float* ln1_b  = (const float*)d_in[3];
  const float* w_qkv  = (const float*)d_in[4];
  const float* w_proj = (const float*)d_in[5];
  const float* b_proj = (const float*)d_in[6];
  const float* ln2_g  = (const float*)d_in[7];
  const float* ln2_b  = (const float*)d_in[8];
  const float* w_fc1  = (const float*)d_in[9];
  const float* b_fc1  = (const float*)d_in[10];
  const float* w_fc2  = (const float*)d_in[11];
  const float* b_fc2  = (const float*)d_in[12];

  // Workspace layout (total 230.3 MB — the R2 footprint that passed):
  //   x    [0,   64) MB   f32 [N][256]
  //   act  [64,  96) MB   bf16 [N][256] (LN out; attn out overwrites it)
  //   big  [96, 224) MB   bf16 [N][1024] (fc1 out); sub-aliases during attn:
  //     q_bf [96,128)  k8 [128,144)  v8 [144,160)
  //   wT   [224, 230.3) MB  transposed bf16 weights
  char* ws = (char*)d_ws;
  float* x    = (float*)(ws);
  short* act  = (short*)(ws + 67108864);
  short* big  = (short*)(ws + 100663296);
  short* q_bf = big;
  uchar* k8   = (uchar*)(ws + 134217728);
  uchar* v8   = (uchar*)(ws + 150994944);
  short* wT   = (short*)(ws + 234881024);
  short* wqkvT  = wT;                // [L][768][256]
  short* wprojT = wT + 786432;       // [L][256][256]
  short* wfc1T  = wT + 1048576;      // [L][1024][256]
  short* wfc2T  = wT + 2097152;      // [L][256][1024]

  wcast<<<dim3(768, 4), 256, 0, stream>>>(w_qkv, wqkvT, 256, 768);
  wcast<<<dim3(256, 4), 256, 0, stream>>>(w_proj, wprojT, 256, 256);
  wcast<<<dim3(1024, 4), 256, 0, stream>>>(w_fc1, wfc1T, 256, 1024);
  wcast<<<dim3(1024, 4), 256, 0, stream>>>(w_fc2, wfc2T, 1024, 256);

  for (int i = 0; i < 4; ++i) {
    const float* xin = (i == 0) ? in_x : x;
    ln_k<<<16384, 256, 0, stream>>>(xin, ln1_g + i * 256, ln1_b + i * 256, act);
    gemm_k<3, 256><<<3072, 256, 0, stream>>>(
        act, wqkvT + (size_t)i * 196608, nullptr, nullptr, q_bf, nullptr,
        k8, v8, 768, 6);
    attn_k<<<16384, 256, 0, stream>>>(q_bf, k8, v8, knn, act);
    gemm_k<1, 256><<<1024, 256, 0, stream>>>(
        act, wprojT + (size_t)i * 65536, b_proj + i * 256, xin, nullptr, x,
        nullptr, nullptr, 256, 2);
    ln_k<<<16384, 256, 0, stream>>>(x, ln2_g + i * 256, ln2_b + i * 256, act);
    gemm_k<2, 256><<<4096, 256, 0, stream>>>(
        act, wfc1T + (size_t)i * 262144, b_fc1 + i * 1024, nullptr, big, nullptr,
        nullptr, nullptr, 1024, 8);
    gemm_k<1, 1024><<<1024, 256, 0, stream>>>(
        big, wfc2T + (size_t)i * 262144, b_fc2 + i * 256, x, nullptr,
        (i == 3) ? (float*)d_out : x, nullptr, nullptr, 256, 2);
  }
}

// Round 9
// 1267.618 us; speedup vs baseline: 1.3454x; 1.0288x over previous
//
#include <hip/hip_runtime.h>

typedef __attribute__((ext_vector_type(4))) float  f32x4;
typedef __attribute__((ext_vector_type(2))) float  f32x2;
typedef __attribute__((ext_vector_type(8))) __bf16 bf16x8;
typedef __attribute__((ext_vector_type(4))) short  s16x4;
typedef __attribute__((ext_vector_type(8))) short  s16x8;
typedef unsigned char uchar;

__device__ __forceinline__ unsigned short f2bf(float f) {
  unsigned u = __builtin_bit_cast(unsigned, f);
  u += 0x7FFFu + ((u >> 16) & 1u);
  return (unsigned short)(u >> 16);
}
__device__ __forceinline__ float b2f(short s) {
  return __builtin_bit_cast(float, (unsigned)((unsigned short)s) << 16);
}
__device__ __forceinline__ uchar f2fp8(float v) {
  return (uchar)(__builtin_amdgcn_cvt_pk_fp8_f32(v, v, 0, false) & 0xFF);
}
__device__ __forceinline__ float gelu_fast(float v) {
  float u = v * (0.7978845608f + 0.0356774081f * v * v);
  float t = __expf(-2.f * fabsf(u));
  float th = (1.f - t) / (1.f + t);
  th = (u >= 0.f) ? th : -th;
  return 0.5f * v * (1.f + th);
}

__device__ __forceinline__ void gload16(const void* g, void* l) {
  __builtin_amdgcn_global_load_lds(
      (const __attribute__((address_space(1))) void*)g,
      (__attribute__((address_space(3))) void*)l, 16, 0, 0);
}

// Transpose + cast weights: W [L][In][Out] f32 -> WT [L][Out][In] bf16
__global__ __launch_bounds__(256) void wcast(const float* __restrict__ W,
                                             short* __restrict__ WT,
                                             int In, int Out) {
  int i = blockIdx.x * 256 + threadIdx.x;
  int lay = blockIdx.y;
  if (i >= In * Out) return;
  const float* w = W + (size_t)lay * In * Out;
  short* wt = WT + (size_t)lay * In * Out;
  int ii = i % In, oo = i / In;
  wt[(size_t)oo * In + ii] = (short)f2bf(w[(size_t)ii * Out + oo]);
}

// LayerNorm over C=256, one wave per row, write bf16
__global__ __launch_bounds__(256) void ln_k(const float* __restrict__ x,
                                            const float* __restrict__ g,
                                            const float* __restrict__ b,
                                            short* __restrict__ out) {
  int row = blockIdx.x * 4 + (threadIdx.x >> 6);
  int l = threadIdx.x & 63;
  const float4 v = *(const float4*)(x + (size_t)row * 256 + l * 4);
  float s  = v.x + v.y + v.z + v.w;
  float ss = v.x * v.x + v.y * v.y + v.z * v.z + v.w * v.w;
#pragma unroll
  for (int o = 32; o >= 1; o >>= 1) {
    s  += __shfl_xor(s, o);
    ss += __shfl_xor(ss, o);
  }
  float mean = s * (1.0f / 256.0f);
  float var  = ss * (1.0f / 256.0f) - mean * mean;
  float rstd = rsqrtf(var + 1e-5f);
  const float4 gg = *(const float4*)(g + l * 4);
  const float4 bb = *(const float4*)(b + l * 4);
  s16x4 o4;
  o4[0] = (short)f2bf((v.x - mean) * rstd * gg.x + bb.x);
  o4[1] = (short)f2bf((v.y - mean) * rstd * gg.y + bb.y);
  o4[2] = (short)f2bf((v.z - mean) * rstd * gg.z + bb.z);
  o4[3] = (short)f2bf((v.w - mean) * rstd * gg.w + bb.w);
  *(s16x4*)(out + (size_t)row * 256 + l * 4) = o4;
}

// KNN attention: one wave per point. q bf16 [N][256], k8/v8 fp8 [N][256]
__global__ __launch_bounds__(256) void attn_k(const short* __restrict__ q_,
                                              const uchar* __restrict__ k8,
                                              const uchar* __restrict__ v8,
                                              const int* __restrict__ knn,
                                              short* __restrict__ out) {
  int n = blockIdx.x * 4 + (threadIdx.x >> 6);
  int l = threadIdx.x & 63;
  int j = l & 15, g = l >> 4;
  int idxj = knn[(size_t)n * 16 + j];
  const short* qp = q_ + (size_t)n * 256 + g * 64;
  const uchar* kp = k8 + (size_t)idxj * 256 + g * 64;
  float partial = 0.f;
#pragma unroll
  for (int t = 0; t < 4; ++t) {  // 16 channels per t
    int4 kv = *(const int4*)(kp + t * 16);
    s16x8 q0 = *(const s16x8*)(qp + t * 16);
    s16x8 q1 = *(const s16x8*)(qp + t * 16 + 8);
    f32x2 a;
    a = __builtin_amdgcn_cvt_pk_f32_fp8(kv.x, false);
    partial += a[0] * b2f(q0[0]) + a[1] * b2f(q0[1]);
    a = __builtin_amdgcn_cvt_pk_f32_fp8(kv.x, true);
    partial += a[0] * b2f(q0[2]) + a[1] * b2f(q0[3]);
    a = __builtin_amdgcn_cvt_pk_f32_fp8(kv.y, false);
    partial += a[0] * b2f(q0[4]) + a[1] * b2f(q0[5]);
    a = __builtin_amdgcn_cvt_pk_f32_fp8(kv.y, true);
    partial += a[0] * b2f(q0[6]) + a[1] * b2f(q0[7]);
    a = __builtin_amdgcn_cvt_pk_f32_fp8(kv.z, false);
    partial += a[0] * b2f(q1[0]) + a[1] * b2f(q1[1]);
    a = __builtin_amdgcn_cvt_pk_f32_fp8(kv.z, true);
    partial += a[0] * b2f(q1[2]) + a[1] * b2f(q1[3]);
    a = __builtin_amdgcn_cvt_pk_f32_fp8(kv.w, false);
    partial += a[0] * b2f(q1[4]) + a[1] * b2f(q1[5]);
    a = __builtin_amdgcn_cvt_pk_f32_fp8(kv.w, true);
    partial += a[0] * b2f(q1[6]) + a[1] * b2f(q1[7]);
  }
  partial += __shfl_xor(partial, 16);
  partial += __shfl_xor(partial, 32);
  float score = partial * 0.0625f;  // C^-0.5, C=256
  float mx = score;
#pragma unroll
  for (int o = 1; o < 16; o <<= 1) mx = fmaxf(mx, __shfl_xor(mx, o));
  float e = __expf(score - mx);
  float sum = e;
#pragma unroll
  for (int o = 1; o < 16; o <<= 1) sum += __shfl_xor(sum, o);
  float attn = e / sum;
  float4 o4 = {0.f, 0.f, 0.f, 0.f};
#pragma unroll
  for (int jj = 0; jj < 16; ++jj) {
    float aj = __shfl(attn, jj);
    int   ij = __shfl(idxj, jj);
    int vv = *(const int*)(v8 + (size_t)ij * 256 + l * 4);
    f32x2 lo = __builtin_amdgcn_cvt_pk_f32_fp8(vv, false);
    f32x2 hi = __builtin_amdgcn_cvt_pk_f32_fp8(vv, true);
    o4.x += aj * lo[0];
    o4.y += aj * lo[1];
    o4.z += aj * hi[0];
    o4.w += aj * hi[1];
  }
  s16x4 ob;
  ob[0] = (short)f2bf(o4.x);
  ob[1] = (short)f2bf(o4.y);
  ob[2] = (short)f2bf(o4.z);
  ob[3] = (short)f2bf(o4.w);
  *(s16x4*)(out + (size_t)n * 256 + l * 4) = ob;
}

// GEMM: A [M][KD] bf16 x BT [Nout][KD] bf16 -> out [M][Nout]
// EPI 1: +bias +resid(f32) -> f32 (scalar-store path).
// EPI 2: +bias, fast-gelu -> bf16 via LDS-transpose epilogue (dwordx4 stores).
// EPI 3: qkv split -> q bf16 / k8 fp8 / v8 fp8, via LDS-transpose epilogue.
// 128x128 tile, BK=64, 4 waves (2x2), T2 XOR swizzle, T1 XCD-chunked swizzle.
template <int EPI, int KD>
__global__ __launch_bounds__(256) void gemm_k(
    const short* __restrict__ A, const short* __restrict__ BT,
    const float* __restrict__ bias, const float* __restrict__ resid,
    short* __restrict__ outb, float* __restrict__ outf,
    uchar* __restrict__ k8, uchar* __restrict__ v8, int Nout, int gx) {
  // pool: staging lA (16K) + lB (16K) during K-loop; re-used as 4 x 9216B
  // wave-private transpose slices in the epilogue (after final barrier).
  __shared__ __align__(16) char pool[36864];
  short* lA = (short*)pool;
  short* lB = (short*)(pool + 16384);
  const int tid = threadIdx.x;
  const int l = tid & 63, w = tid >> 6;
  const int nwg = gridDim.x;
  const int bid = blockIdx.x;
  const int swz = (bid & 7) * (nwg >> 3) + (bid >> 3);
  const int m0 = (swz / gx) << 7, n0 = (swz % gx) << 7;
  const int wm = w >> 1, wn = w & 1;

  f32x4 acc[4][4];
#pragma unroll
  for (int i = 0; i < 4; ++i)
#pragma unroll
    for (int jj = 0; jj < 4; ++jj) acc[i][jj] = f32x4{0.f, 0.f, 0.f, 0.f};

  const int srow = (w << 3) + (l >> 3);
  const int scol = (((l & 7) << 3)) ^ ((srow & 7) << 3);
  const short* gA = A + (size_t)(m0 + srow) * KD + scol;
  const short* gB = BT + (size_t)(n0 + srow) * KD + scol;

  for (int kt = 0; kt < KD; kt += 64) {
#pragma unroll
    for (int it = 0; it < 4; ++it) {
      gload16(gA + (size_t)(it * 32) * KD + kt, &lA[(it * 32 + w * 8) * 64]);
      gload16(gB + (size_t)(it * 32) * KD + kt, &lB[(it * 32 + w * 8) * 64]);
    }
    __syncthreads();
#pragma unroll
    for (int kc = 0; kc < 2; ++kc) {
      bf16x8 aF[4], bF[4];
#pragma unroll
      for (int f = 0; f < 4; ++f) {
        int r = wm * 64 + f * 16 + (l & 15);
        int ce = (kc * 32 + ((l >> 4) << 3)) ^ ((r & 7) << 3);
        aF[f] = *(const bf16x8*)(lA + r * 64 + ce);
      }
#pragma unroll
      for (int f = 0; f < 4; ++f) {
        int r = wn * 64 + f * 16 + (l & 15);
        int ce = (kc * 32 + ((l >> 4) << 3)) ^ ((r & 7) << 3);
        bF[f] = *(const bf16x8*)(lB + r * 64 + ce);
      }
#pragma unroll
      for (int mf = 0; mf < 4; ++mf)
#pragma unroll
        for (int nf = 0; nf < 4; ++nf)
          acc[mf][nf] = __builtin_amdgcn_mfma_f32_16x16x32_bf16(
              aF[mf], bF[nf], acc[mf][nf], 0, 0, 0);
    }
    __syncthreads();
  }

  const int lr = (l >> 4) << 2, lc = l & 15;
  if (EPI == 1) {
#pragma unroll
    for (int mf = 0; mf < 4; ++mf) {
#pragma unroll
      for (int nf = 0; nf < 4; ++nf) {
#pragma unroll
        for (int jj = 0; jj < 4; ++jj) {
          int row = m0 + wm * 64 + mf * 16 + lr + jj;
          int col = n0 + wn * 64 + nf * 16 + lc;
          float v = acc[mf][nf][jj] + bias[col] + resid[(size_t)row * 256 + col];
          outf[(size_t)row * 256 + col] = v;
        }
      }
    }
    return;
  }

  // EPI 2/3: wave-private LDS transpose -> 16B/lane coalesced stores.
  // Slice: 64 rows x 64 cols bf16, row stride 72 shorts (144B, 16B-aligned).
  short* myL = (short*)(pool + w * 9216);
#pragma unroll
  for (int mf = 0; mf < 4; ++mf) {
#pragma unroll
    for (int nf = 0; nf < 4; ++nf) {
#pragma unroll
      for (int jj = 0; jj < 4; ++jj) {
        int rl = mf * 16 + lr + jj;
        int cl = nf * 16 + lc;
        float v = acc[mf][nf][jj];
        if (EPI == 2) v = gelu_fast(v + bias[n0 + wn * 64 + cl]);
        myL[rl * 72 + cl] = (short)f2bf(v);
      }
    }
  }
  // wave-private region: ds_write -> ds_read ordered by lgkmcnt (compiler).
#pragma unroll
  for (int it = 0; it < 8; ++it) {
    int rl = it * 8 + (l >> 3);
    int cl = (l & 7) * 8;
    s16x8 vv = *(const s16x8*)(myL + rl * 72 + cl);
    int rowg = m0 + wm * 64 + rl;
    int colg = n0 + wn * 64 + cl;
    if (EPI == 2) {
      *(s16x8*)(outb + (size_t)rowg * Nout + colg) = vv;
    } else {  // EPI 3: qkv split (col-block uniform per wave-tile)
      if (colg < 256) {
        *(s16x8*)(outb + (size_t)rowg * 256 + colg) = vv;
      } else {
        unsigned w0 = __builtin_amdgcn_cvt_pk_fp8_f32(b2f(vv[0]), b2f(vv[1]), 0, false);
        w0 = __builtin_amdgcn_cvt_pk_fp8_f32(b2f(vv[2]), b2f(vv[3]), w0, true);
        unsigned w1 = __builtin_amdgcn_cvt_pk_fp8_f32(b2f(vv[4]), b2f(vv[5]), 0, false);
        w1 = __builtin_amdgcn_cvt_pk_fp8_f32(b2f(vv[6]), b2f(vv[7]), w1, true);
        int2 pk = make_int2((int)w0, (int)w1);
        uchar* dst = (colg < 512) ? (k8 + (size_t)rowg * 256 + (colg - 256))
                                  : (v8 + (size_t)rowg * 256 + (colg - 512));
        *(int2*)dst = pk;
      }
    }
  }
}

extern "C" void kernel_launch(void* const* d_in, const int* in_sizes, int n_in,
                              void* d_out, int out_size, void* d_ws, size_t ws_size,
                              hipStream_t stream) {
  const float* in_x   = (const float*)d_in[0];
  const int*   knn    = (const int*)d_in[1];
  const float* ln1_g  = (const float*)d_in[2];
  const float* ln1_b  = (const float*)d_in[3];
  const float* w_qkv  = (const float*)d_in[4];
  const float* w_proj = (const float*)d_in[5];
  const float* b_proj = (const float*)d_in[6];
  const float* ln2_g  = (const float*)d_in[7];
  const float* ln2_b  = (const float*)d_in[8];
  const float* w_fc1  = (const float*)d_in[9];
  const float* b_fc1  = (const float*)d_in[10];
  const float* w_fc2  = (const float*)d_in[11];
  const float* b_fc2  = (const float*)d_in[12];

  // Workspace layout (total 230.3 MB):
  //   x    [0,   64) MB   f32 [N][256]
  //   act  [64,  96) MB   bf16 [N][256] (LN out; attn out overwrites it)
  //   big  [96, 224) MB   bf16 [N][1024] (fc1 out); sub-aliases during attn:
  //     q_bf [96,128)  k8 [128,144)  v8 [144,160)
  //   wT   [224, 230.3) MB  transposed bf16 weights
  char* ws = (char*)d_ws;
  float* x    = (float*)(ws);
  short* act  = (short*)(ws + 67108864);
  short* big  = (short*)(ws + 100663296);
  short* q_bf = big;
  uchar* k8   = (uchar*)(ws + 134217728);
  uchar* v8   = (uchar*)(ws + 150994944);
  short* wT   = (short*)(ws + 234881024);
  short* wqkvT  = wT;                // [L][768][256]
  short* wprojT = wT + 786432;       // [L][256][256]
  short* wfc1T  = wT + 1048576;      // [L][1024][256]
  short* wfc2T  = wT + 2097152;      // [L][256][1024]

  wcast<<<dim3(768, 4), 256, 0, stream>>>(w_qkv, wqkvT, 256, 768);
  wcast<<<dim3(256, 4), 256, 0, stream>>>(w_proj, wprojT, 256, 256);
  wcast<<<dim3(1024, 4), 256, 0, stream>>>(w_fc1, wfc1T, 256, 1024);
  wcast<<<dim3(1024, 4), 256, 0, stream>>>(w_fc2, wfc2T, 1024, 256);

  for (int i = 0; i < 4; ++i) {
    const float* xin = (i == 0) ? in_x : x;
    ln_k<<<16384, 256, 0, stream>>>(xin, ln1_g + i * 256, ln1_b + i * 256, act);
    gemm_k<3, 256><<<3072, 256, 0, stream>>>(
        act, wqkvT + (size_t)i * 196608, nullptr, nullptr, q_bf, nullptr,
        k8, v8, 768, 6);
    attn_k<<<16384, 256, 0, stream>>>(q_bf, k8, v8, knn, act);
    gemm_k<1, 256><<<1024, 256, 0, stream>>>(
        act, wprojT + (size_t)i * 65536, b_proj + i * 256, xin, nullptr, x,
        nullptr, nullptr, 256, 2);
    ln_k<<<16384, 256, 0, stream>>>(x, ln2_g + i * 256, ln2_b + i * 256, act);
    gemm_k<2, 256><<<4096, 256, 0, stream>>>(
        act, wfc1T + (size_t)i * 262144, b_fc1 + i * 1024, nullptr, big, nullptr,
        nullptr, nullptr, 1024, 8);
    gemm_k<1, 1024><<<1024, 256, 0, stream>>>(
        big, wfc2T + (size_t)i * 262144, b_fc2 + i * 256, x, nullptr,
        (i == 3) ? (float*)d_out : x, nullptr, nullptr, 256, 2);
  }
}

// Round 10
// 1248.381 us; speedup vs baseline: 1.3662x; 1.0154x over previous
//
#include <hip/hip_runtime.h>

typedef __attribute__((ext_vector_type(4))) float  f32x4;
typedef __attribute__((ext_vector_type(2))) float  f32x2;
typedef __attribute__((ext_vector_type(8))) __bf16 bf16x8;
typedef __attribute__((ext_vector_type(4))) short  s16x4;
typedef __attribute__((ext_vector_type(8))) short  s16x8;
typedef unsigned char uchar;

__device__ __forceinline__ unsigned short f2bf(float f) {
  unsigned u = __builtin_bit_cast(unsigned, f);
  u += 0x7FFFu + ((u >> 16) & 1u);
  return (unsigned short)(u >> 16);
}
__device__ __forceinline__ float b2f(short s) {
  return __builtin_bit_cast(float, (unsigned)((unsigned short)s) << 16);
}
__device__ __forceinline__ uchar f2fp8(float v) {
  return (uchar)(__builtin_amdgcn_cvt_pk_fp8_f32(v, v, 0, false) & 0xFF);
}
__device__ __forceinline__ float gelu_fast(float v) {
  float u = v * (0.7978845608f + 0.0356774081f * v * v);
  float t = __expf(-2.f * fabsf(u));
  float th = (1.f - t) / (1.f + t);
  th = (u >= 0.f) ? th : -th;
  return 0.5f * v * (1.f + th);
}

__device__ __forceinline__ void gload16(const void* g, void* l) {
  __builtin_amdgcn_global_load_lds(
      (const __attribute__((address_space(1))) void*)g,
      (__attribute__((address_space(3))) void*)l, 16, 0, 0);
}

// Transpose + cast weights: W [L][In][Out] f32 -> WT [L][Out][In] bf16
__global__ __launch_bounds__(256) void wcast(const float* __restrict__ W,
                                             short* __restrict__ WT,
                                             int In, int Out) {
  int i = blockIdx.x * 256 + threadIdx.x;
  int lay = blockIdx.y;
  if (i >= In * Out) return;
  const float* w = W + (size_t)lay * In * Out;
  short* wt = WT + (size_t)lay * In * Out;
  int ii = i % In, oo = i / In;
  wt[(size_t)oo * In + ii] = (short)f2bf(w[(size_t)ii * Out + oo]);
}

// w_fc2 [L][1024][256] f32 -> fp8 [L][256][1024], scaled x64
__global__ __launch_bounds__(256) void wcast8(const float* __restrict__ W,
                                              uchar* __restrict__ WT8) {
  int i = blockIdx.x * 256 + threadIdx.x;  // over 1024*256
  int lay = blockIdx.y;
  const float* w = W + (size_t)lay * 262144;
  uchar* wt = WT8 + (size_t)lay * 262144;
  int ii = i % 1024, oo = i / 1024;  // ii = K index, oo = out col
  wt[(size_t)oo * 1024 + ii] = f2fp8(64.f * w[(size_t)ii * 256 + oo]);
}

// LayerNorm over C=256, one wave per row, write bf16
__global__ __launch_bounds__(256) void ln_k(const float* __restrict__ x,
                                            const float* __restrict__ g,
                                            const float* __restrict__ b,
                                            short* __restrict__ out) {
  int row = blockIdx.x * 4 + (threadIdx.x >> 6);
  int l = threadIdx.x & 63;
  const float4 v = *(const float4*)(x + (size_t)row * 256 + l * 4);
  float s  = v.x + v.y + v.z + v.w;
  float ss = v.x * v.x + v.y * v.y + v.z * v.z + v.w * v.w;
#pragma unroll
  for (int o = 32; o >= 1; o >>= 1) {
    s  += __shfl_xor(s, o);
    ss += __shfl_xor(ss, o);
  }
  float mean = s * (1.0f / 256.0f);
  float var  = ss * (1.0f / 256.0f) - mean * mean;
  float rstd = rsqrtf(var + 1e-5f);
  const float4 gg = *(const float4*)(g + l * 4);
  const float4 bb = *(const float4*)(b + l * 4);
  s16x4 o4;
  o4[0] = (short)f2bf((v.x - mean) * rstd * gg.x + bb.x);
  o4[1] = (short)f2bf((v.y - mean) * rstd * gg.y + bb.y);
  o4[2] = (short)f2bf((v.z - mean) * rstd * gg.z + bb.z);
  o4[3] = (short)f2bf((v.w - mean) * rstd * gg.w + bb.w);
  *(s16x4*)(out + (size_t)row * 256 + l * 4) = o4;
}

// KNN attention: one wave per point. q bf16 [N][256], k8/v8 fp8 [N][256]
__global__ __launch_bounds__(256) void attn_k(const short* __restrict__ q_,
                                              const uchar* __restrict__ k8,
                                              const uchar* __restrict__ v8,
                                              const int* __restrict__ knn,
                                              short* __restrict__ out) {
  int n = blockIdx.x * 4 + (threadIdx.x >> 6);
  int l = threadIdx.x & 63;
  int j = l & 15, g = l >> 4;
  int idxj = knn[(size_t)n * 16 + j];
  const short* qp = q_ + (size_t)n * 256 + g * 64;
  const uchar* kp = k8 + (size_t)idxj * 256 + g * 64;
  float partial = 0.f;
#pragma unroll
  for (int t = 0; t < 4; ++t) {  // 16 channels per t
    int4 kv = *(const int4*)(kp + t * 16);
    s16x8 q0 = *(const s16x8*)(qp + t * 16);
    s16x8 q1 = *(const s16x8*)(qp + t * 16 + 8);
    f32x2 a;
    a = __builtin_amdgcn_cvt_pk_f32_fp8(kv.x, false);
    partial += a[0] * b2f(q0[0]) + a[1] * b2f(q0[1]);
    a = __builtin_amdgcn_cvt_pk_f32_fp8(kv.x, true);
    partial += a[0] * b2f(q0[2]) + a[1] * b2f(q0[3]);
    a = __builtin_amdgcn_cvt_pk_f32_fp8(kv.y, false);
    partial += a[0] * b2f(q0[4]) + a[1] * b2f(q0[5]);
    a = __builtin_amdgcn_cvt_pk_f32_fp8(kv.y, true);
    partial += a[0] * b2f(q0[6]) + a[1] * b2f(q0[7]);
    a = __builtin_amdgcn_cvt_pk_f32_fp8(kv.z, false);
    partial += a[0] * b2f(q1[0]) + a[1] * b2f(q1[1]);
    a = __builtin_amdgcn_cvt_pk_f32_fp8(kv.z, true);
    partial += a[0] * b2f(q1[2]) + a[1] * b2f(q1[3]);
    a = __builtin_amdgcn_cvt_pk_f32_fp8(kv.w, false);
    partial += a[0] * b2f(q1[4]) + a[1] * b2f(q1[5]);
    a = __builtin_amdgcn_cvt_pk_f32_fp8(kv.w, true);
    partial += a[0] * b2f(q1[6]) + a[1] * b2f(q1[7]);
  }
  partial += __shfl_xor(partial, 16);
  partial += __shfl_xor(partial, 32);
  float score = partial * 0.0625f;  // C^-0.5, C=256
  float mx = score;
#pragma unroll
  for (int o = 1; o < 16; o <<= 1) mx = fmaxf(mx, __shfl_xor(mx, o));
  float e = __expf(score - mx);
  float sum = e;
#pragma unroll
  for (int o = 1; o < 16; o <<= 1) sum += __shfl_xor(sum, o);
  float attn = e / sum;
  float4 o4 = {0.f, 0.f, 0.f, 0.f};
#pragma unroll
  for (int jj = 0; jj < 16; ++jj) {
    float aj = __shfl(attn, jj);
    int   ij = __shfl(idxj, jj);
    int vv = *(const int*)(v8 + (size_t)ij * 256 + l * 4);
    f32x2 lo = __builtin_amdgcn_cvt_pk_f32_fp8(vv, false);
    f32x2 hi = __builtin_amdgcn_cvt_pk_f32_fp8(vv, true);
    o4.x += aj * lo[0];
    o4.y += aj * lo[1];
    o4.z += aj * hi[0];
    o4.w += aj * hi[1];
  }
  s16x4 ob;
  ob[0] = (short)f2bf(o4.x);
  ob[1] = (short)f2bf(o4.y);
  ob[2] = (short)f2bf(o4.z);
  ob[3] = (short)f2bf(o4.w);
  *(s16x4*)(out + (size_t)n * 256 + l * 4) = ob;
}

// GEMM: A [M][KD] bf16 x BT [Nout][KD] bf16 -> out [M][Nout]
// EPI 1: +bias +resid(f32) -> f32 (scalar-store path).
// EPI 2: +bias, fast-gelu -> fp8 (x16 scale) via LDS-transpose epilogue.
// EPI 3: qkv split -> q bf16 / k8 fp8 / v8 fp8, via LDS-transpose epilogue.
// 128x128 tile, BK=64, 4 waves (2x2), T2 XOR swizzle, T1 XCD-chunked swizzle.
template <int EPI, int KD>
__global__ __launch_bounds__(256) void gemm_k(
    const short* __restrict__ A, const short* __restrict__ BT,
    const float* __restrict__ bias, const float* __restrict__ resid,
    short* __restrict__ outb, float* __restrict__ outf,
    uchar* __restrict__ k8, uchar* __restrict__ v8, int Nout, int gx) {
  __shared__ __align__(16) char pool[36864];
  short* lA = (short*)pool;
  short* lB = (short*)(pool + 16384);
  const int tid = threadIdx.x;
  const int l = tid & 63, w = tid >> 6;
  const int nwg = gridDim.x;
  const int bid = blockIdx.x;
  const int swz = (bid & 7) * (nwg >> 3) + (bid >> 3);
  const int m0 = (swz / gx) << 7, n0 = (swz % gx) << 7;
  const int wm = w >> 1, wn = w & 1;

  f32x4 acc[4][4];
#pragma unroll
  for (int i = 0; i < 4; ++i)
#pragma unroll
    for (int jj = 0; jj < 4; ++jj) acc[i][jj] = f32x4{0.f, 0.f, 0.f, 0.f};

  const int srow = (w << 3) + (l >> 3);
  const int scol = (((l & 7) << 3)) ^ ((srow & 7) << 3);
  const short* gA = A + (size_t)(m0 + srow) * KD + scol;
  const short* gB = BT + (size_t)(n0 + srow) * KD + scol;

  for (int kt = 0; kt < KD; kt += 64) {
#pragma unroll
    for (int it = 0; it < 4; ++it) {
      gload16(gA + (size_t)(it * 32) * KD + kt, &lA[(it * 32 + w * 8) * 64]);
      gload16(gB + (size_t)(it * 32) * KD + kt, &lB[(it * 32 + w * 8) * 64]);
    }
    __syncthreads();
#pragma unroll
    for (int kc = 0; kc < 2; ++kc) {
      bf16x8 aF[4], bF[4];
#pragma unroll
      for (int f = 0; f < 4; ++f) {
        int r = wm * 64 + f * 16 + (l & 15);
        int ce = (kc * 32 + ((l >> 4) << 3)) ^ ((r & 7) << 3);
        aF[f] = *(const bf16x8*)(lA + r * 64 + ce);
      }
#pragma unroll
      for (int f = 0; f < 4; ++f) {
        int r = wn * 64 + f * 16 + (l & 15);
        int ce = (kc * 32 + ((l >> 4) << 3)) ^ ((r & 7) << 3);
        bF[f] = *(const bf16x8*)(lB + r * 64 + ce);
      }
#pragma unroll
      for (int mf = 0; mf < 4; ++mf)
#pragma unroll
        for (int nf = 0; nf < 4; ++nf)
          acc[mf][nf] = __builtin_amdgcn_mfma_f32_16x16x32_bf16(
              aF[mf], bF[nf], acc[mf][nf], 0, 0, 0);
    }
    __syncthreads();
  }

  const int lr = (l >> 4) << 2, lc = l & 15;
  if (EPI == 1) {
#pragma unroll
    for (int mf = 0; mf < 4; ++mf) {
#pragma unroll
      for (int nf = 0; nf < 4; ++nf) {
#pragma unroll
        for (int jj = 0; jj < 4; ++jj) {
          int row = m0 + wm * 64 + mf * 16 + lr + jj;
          int col = n0 + wn * 64 + nf * 16 + lc;
          float v = acc[mf][nf][jj] + bias[col] + resid[(size_t)row * 256 + col];
          outf[(size_t)row * 256 + col] = v;
        }
      }
    }
    return;
  }

  // EPI 2/3: wave-private LDS transpose -> coalesced packed stores.
  short* myL = (short*)(pool + w * 9216);
#pragma unroll
  for (int mf = 0; mf < 4; ++mf) {
#pragma unroll
    for (int nf = 0; nf < 4; ++nf) {
#pragma unroll
      for (int jj = 0; jj < 4; ++jj) {
        int rl = mf * 16 + lr + jj;
        int cl = nf * 16 + lc;
        float v = acc[mf][nf][jj];
        if (EPI == 2) v = gelu_fast(v + bias[n0 + wn * 64 + cl]);
        myL[rl * 72 + cl] = (short)f2bf(v);
      }
    }
  }
#pragma unroll
  for (int it = 0; it < 8; ++it) {
    int rl = it * 8 + (l >> 3);
    int cl = (l & 7) * 8;
    s16x8 vv = *(const s16x8*)(myL + rl * 72 + cl);
    int rowg = m0 + wm * 64 + rl;
    int colg = n0 + wn * 64 + cl;
    if (EPI == 2) {
      // pack gelu output x16 -> fp8, 8B/lane
      unsigned w0 = __builtin_amdgcn_cvt_pk_fp8_f32(16.f * b2f(vv[0]), 16.f * b2f(vv[1]), 0, false);
      w0 = __builtin_amdgcn_cvt_pk_fp8_f32(16.f * b2f(vv[2]), 16.f * b2f(vv[3]), w0, true);
      unsigned w1 = __builtin_amdgcn_cvt_pk_fp8_f32(16.f * b2f(vv[4]), 16.f * b2f(vv[5]), 0, false);
      w1 = __builtin_amdgcn_cvt_pk_fp8_f32(16.f * b2f(vv[6]), 16.f * b2f(vv[7]), w1, true);
      *(int2*)(k8 + (size_t)rowg * Nout + colg) = make_int2((int)w0, (int)w1);
    } else {  // EPI 3: qkv split
      if (colg < 256) {
        *(s16x8*)(outb + (size_t)rowg * 256 + colg) = vv;
      } else {
        unsigned w0 = __builtin_amdgcn_cvt_pk_fp8_f32(b2f(vv[0]), b2f(vv[1]), 0, false);
        w0 = __builtin_amdgcn_cvt_pk_fp8_f32(b2f(vv[2]), b2f(vv[3]), w0, true);
        unsigned w1 = __builtin_amdgcn_cvt_pk_fp8_f32(b2f(vv[4]), b2f(vv[5]), 0, false);
        w1 = __builtin_amdgcn_cvt_pk_fp8_f32(b2f(vv[6]), b2f(vv[7]), w1, true);
        int2 pk = make_int2((int)w0, (int)w1);
        uchar* dst = (colg < 512) ? (k8 + (size_t)rowg * 256 + (colg - 256))
                                  : (v8 + (size_t)rowg * 256 + (colg - 512));
        *(int2*)dst = pk;
      }
    }
  }
}

// fc2: A8 fp8 [M][1024] (a1 x16) x B8 fp8 [256][1024] (w x64) -> f32
// out = acc/1024 + bias + resid. 128x128 tile, BK=64, fp8 MFMA.
// LDS tiles [128][64] bytes, 16B-granule XOR swizzle (c ^= (r&3)<<4).
__global__ __launch_bounds__(256) void gemm_fp8(
    const uchar* __restrict__ A8, const uchar* __restrict__ B8,
    const float* __restrict__ bias, const float* __restrict__ resid,
    float* __restrict__ outf) {
  __shared__ __align__(16) uchar lA8[8192];
  __shared__ __align__(16) uchar lB8[8192];
  const int tid = threadIdx.x;
  const int l = tid & 63, w = tid >> 6;
  const int nwg = gridDim.x;
  const int bid = blockIdx.x;
  const int swz = (bid & 7) * (nwg >> 3) + (bid >> 3);
  const int m0 = (swz >> 1) << 7, n0 = (swz & 1) << 7;
  const int wm = w >> 1, wn = w & 1;

  f32x4 acc[4][4];
#pragma unroll
  for (int i = 0; i < 4; ++i)
#pragma unroll
    for (int jj = 0; jj < 4; ++jj) acc[i][jj] = f32x4{0.f, 0.f, 0.f, 0.f};

  // staging: per it, wave covers 16 rows x 64B; lane -> row (l>>2), 16B chunk (l&3)
  const int sr = (w << 4) + (l >> 2);               // row within 64-row half
  const int sc = ((l & 3) << 4) ^ ((sr & 3) << 4);  // pre-swizzled source col
  const uchar* gA = A8 + (size_t)(m0 + sr) * 1024 + sc;
  const uchar* gB = B8 + (size_t)(n0 + sr) * 1024 + sc;

  for (int kt = 0; kt < 1024; kt += 64) {
#pragma unroll
    for (int it = 0; it < 2; ++it) {
      gload16(gA + (size_t)(it * 64) * 1024 + kt, &lA8[(it * 64 + w * 16) * 64]);
      gload16(gB + (size_t)(it * 64) * 1024 + kt, &lB8[(it * 64 + w * 16) * 64]);
    }
    __syncthreads();
#pragma unroll
    for (int kc = 0; kc < 2; ++kc) {
      long aF[4], bF[4];
#pragma unroll
      for (int f = 0; f < 4; ++f) {
        int r = wm * 64 + f * 16 + (l & 15);
        int cs = (kc * 32 + ((l >> 4) << 3)) ^ ((r & 3) << 4);
        aF[f] = *(const long*)(lA8 + r * 64 + cs);
      }
#pragma unroll
      for (int f = 0; f < 4; ++f) {
        int r = wn * 64 + f * 16 + (l & 15);
        int cs = (kc * 32 + ((l >> 4) << 3)) ^ ((r & 3) << 4);
        bF[f] = *(const long*)(lB8 + r * 64 + cs);
      }
#pragma unroll
      for (int mf = 0; mf < 4; ++mf)
#pragma unroll
        for (int nf = 0; nf < 4; ++nf)
          acc[mf][nf] = __builtin_amdgcn_mfma_f32_16x16x32_fp8_fp8(
              aF[mf], bF[nf], acc[mf][nf], 0, 0, 0);
    }
    __syncthreads();
  }

  const int lr = (l >> 4) << 2, lc = l & 15;
#pragma unroll
  for (int mf = 0; mf < 4; ++mf) {
#pragma unroll
    for (int nf = 0; nf < 4; ++nf) {
#pragma unroll
      for (int jj = 0; jj < 4; ++jj) {
        int row = m0 + wm * 64 + mf * 16 + lr + jj;
        int col = n0 + wn * 64 + nf * 16 + lc;
        float v = acc[mf][nf][jj] * (1.0f / 1024.0f) + bias[col] +
                  resid[(size_t)row * 256 + col];
        outf[(size_t)row * 256 + col] = v;
      }
    }
  }
}

extern "C" void kernel_launch(void* const* d_in, const int* in_sizes, int n_in,
                              void* d_out, int out_size, void* d_ws, size_t ws_size,
                              hipStream_t stream) {
  const float* in_x   = (const float*)d_in[0];
  const int*   knn    = (const int*)d_in[1];
  const float* ln1_g  = (const float*)d_in[2];
  const float* ln1_b  = (const float*)d_in[3];
  const float* w_qkv  = (const float*)d_in[4];
  const float* w_proj = (const float*)d_in[5];
  const float* b_proj = (const float*)d_in[6];
  const float* ln2_g  = (const float*)d_in[7];
  const float* ln2_b  = (const float*)d_in[8];
  const float* w_fc1  = (const float*)d_in[9];
  const float* b_fc1  = (const float*)d_in[10];
  const float* w_fc2  = (const float*)d_in[11];
  const float* b_fc2  = (const float*)d_in[12];

  // Workspace layout (max 230.3 MB):
  //   x    [0,   64) MB   f32 [N][256]
  //   act  [64,  96) MB   bf16 [N][256]
  //   big8 [96, 160) MB   fp8 [N][1024] (fc1 out, x16)
  //   q_bf [160,192) MB   bf16 [N][256]
  //   k8   [192,208) MB   fp8 [N][256]
  //   v8   [208,224) MB   fp8 [N][256]
  //   wT   [224, 230.3) MB  converted weights
  char* ws = (char*)d_ws;
  float* x    = (float*)(ws);
  short* act  = (short*)(ws + 67108864);
  uchar* big8 = (uchar*)(ws + 100663296);
  short* q_bf = (short*)(ws + 167772160);
  uchar* k8   = (uchar*)(ws + 201326592);
  uchar* v8   = (uchar*)(ws + 218103808);
  short* wT   = (short*)(ws + 234881024);
  short* wqkvT  = wT;                        // [L][768][256] bf16
  short* wprojT = wT + 786432;               // [L][256][256] bf16
  short* wfc1T  = wT + 1048576;              // [L][1024][256] bf16
  uchar* wfc2T8 = (uchar*)(wT + 2097152);    // [L][256][1024] fp8 (x64)

  wcast<<<dim3(768, 4), 256, 0, stream>>>(w_qkv, wqkvT, 256, 768);
  wcast<<<dim3(256, 4), 256, 0, stream>>>(w_proj, wprojT, 256, 256);
  wcast<<<dim3(1024, 4), 256, 0, stream>>>(w_fc1, wfc1T, 256, 1024);
  wcast8<<<dim3(1024, 4), 256, 0, stream>>>(w_fc2, wfc2T8);

  for (int i = 0; i < 4; ++i) {
    const float* xin = (i == 0) ? in_x : x;
    ln_k<<<16384, 256, 0, stream>>>(xin, ln1_g + i * 256, ln1_b + i * 256, act);
    gemm_k<3, 256><<<3072, 256, 0, stream>>>(
        act, wqkvT + (size_t)i * 196608, nullptr, nullptr, q_bf, nullptr,
        k8, v8, 768, 6);
    attn_k<<<16384, 256, 0, stream>>>(q_bf, k8, v8, knn, act);
    gemm_k<1, 256><<<1024, 256, 0, stream>>>(
        act, wprojT + (size_t)i * 65536, b_proj + i * 256, xin, nullptr, x,
        nullptr, nullptr, 256, 2);
    ln_k<<<16384, 256, 0, stream>>>(x, ln2_g + i * 256, ln2_b + i * 256, act);
    gemm_k<2, 256><<<4096, 256, 0, stream>>>(
        act, wfc1T + (size_t)i * 262144, b_fc1 + i * 1024, nullptr, nullptr,
        nullptr, big8, nullptr, 1024, 8);
    gemm_fp8<<<1024, 256, 0, stream>>>(
        big8, wfc2T8 + (size_t)i * 262144, b_fc2 + i * 256, x,
        (i == 3) ? (float*)d_out : x);
  }
}